// Round 1
// baseline (501.043 us; speedup 1.0000x reference)
//
#include <hip/hip_runtime.h>
#include <hip/hip_bf16.h>

// Problem constants (match reference)
#define NN 32768
#define GG 256
#define NPG 128
#define EE 262144
#define DD 256

// ---------------- graph preprocessing ----------------

__global__ void k_deg(const int* __restrict__ dst, float* __restrict__ deg, int e_count) {
    int e = blockIdx.x * 256 + threadIdx.x;
    if (e < e_count) atomicAdd(&deg[dst[e]], 1.0f);
}

__global__ void k_dinv(float* __restrict__ deg, int n) {
    int i = blockIdx.x * 256 + threadIdx.x;
    if (i < n) deg[i] = rsqrtf(deg[i] + 1.0f);
}

__global__ void k_buildA(const int* __restrict__ src, const int* __restrict__ dst,
                         const float* __restrict__ dinv, float* __restrict__ A, int e_count) {
    int e = blockIdx.x * 256 + threadIdx.x;
    if (e >= e_count) return;
    int s = src[e], d = dst[e];
    int g = d >> 7;
    int i = d & 127, j = s & 127;
    atomicAdd(&A[(((size_t)g * NPG) + i) * NPG + j], dinv[s] * dinv[d]);
}

__global__ void k_diagA(const float* __restrict__ dinv, float* __restrict__ A, int n) {
    int v = blockIdx.x * 256 + threadIdx.x;
    if (v < n) {
        int g = v >> 7, l = v & 127;
        A[(((size_t)g * NPG) + l) * NPG + l] += dinv[v] * dinv[v];
    }
}

// ---------------- shared fp32 tile core ----------------
// 128x128 output tile, BK=16, 256 threads, 8x8 per thread.

__device__ __forceinline__ void mm_inner(const float (*As)[128], const float (*Bs)[128],
                                         int tr, int tc, float acc[8][8]) {
#pragma unroll
    for (int kk = 0; kk < 16; ++kk) {
        float4 a0 = *(const float4*)&As[kk][tr * 8];
        float4 a1 = *(const float4*)&As[kk][tr * 8 + 4];
        float4 b0 = *(const float4*)&Bs[kk][tc * 8];
        float4 b1 = *(const float4*)&Bs[kk][tc * 8 + 4];
        float a[8] = {a0.x, a0.y, a0.z, a0.w, a1.x, a1.y, a1.z, a1.w};
        float b[8] = {b0.x, b0.y, b0.z, b0.w, b1.x, b1.y, b1.z, b1.w};
#pragma unroll
        for (int m = 0; m < 8; ++m)
#pragma unroll
            for (int n = 0; n < 8; ++n)
                acc[m][n] = fmaf(a[m], b[n], acc[m][n]);
    }
}

// ---------------- node GEMM: Y[M,256] = X[M,256] @ W[256,256] ----------------
// grid: (2, M/128)

__global__ __launch_bounds__(256, 2) void k_gemm_nodes(const float* __restrict__ X,
                                                       const float* __restrict__ W,
                                                       float* __restrict__ Y) {
    __shared__ float As[16][128], Bs[16][128];
    const int tid = threadIdx.x;
    const int row0 = blockIdx.y * 128;
    const int col0 = blockIdx.x * 128;
    const int tr = tid >> 4, tc = tid & 15;
    float acc[8][8] = {};
    const int ar = tid >> 1;           // 0..127 (row within tile)
    const int ak = (tid & 1) * 8;      // 0 or 8 (k offset)
    const int bk = tid >> 4;           // 0..15
    const int bc = (tid & 15) * 8;     // col offset
    for (int k0 = 0; k0 < 256; k0 += 16) {
        float4 av0 = *(const float4*)(X + (size_t)(row0 + ar) * 256 + k0 + ak);
        float4 av1 = *(const float4*)(X + (size_t)(row0 + ar) * 256 + k0 + ak + 4);
        float4 bv0 = *(const float4*)(W + (size_t)(k0 + bk) * 256 + col0 + bc);
        float4 bv1 = *(const float4*)(W + (size_t)(k0 + bk) * 256 + col0 + bc + 4);
        __syncthreads();
        As[ak + 0][ar] = av0.x; As[ak + 1][ar] = av0.y;
        As[ak + 2][ar] = av0.z; As[ak + 3][ar] = av0.w;
        As[ak + 4][ar] = av1.x; As[ak + 5][ar] = av1.y;
        As[ak + 6][ar] = av1.z; As[ak + 7][ar] = av1.w;
        *(float4*)&Bs[bk][bc] = bv0;
        *(float4*)&Bs[bk][bc + 4] = bv1;
        __syncthreads();
        mm_inner(As, Bs, tr, tc, acc);
    }
#pragma unroll
    for (int m = 0; m < 8; ++m) {
        float4 o0 = {acc[m][0], acc[m][1], acc[m][2], acc[m][3]};
        float4 o1 = {acc[m][4], acc[m][5], acc[m][6], acc[m][7]};
        float* p = Y + (size_t)(row0 + tr * 8 + m) * 256 + col0 + tc * 8;
        *(float4*)p = o0;
        *(float4*)(p + 4) = o1;
    }
}

// ---------------- propagation: Out_g[128,256] = A_g @ H_g, + bias, opt relu ----
// grid: (2, 1, G)

__global__ __launch_bounds__(256, 2) void k_prop(const float* __restrict__ Amat,
                                                 const float* __restrict__ H,
                                                 const float* __restrict__ bias,
                                                 float* __restrict__ Out, int do_relu) {
    __shared__ float As[16][128], Bs[16][128];
    const int tid = threadIdx.x;
    const int g = blockIdx.z;
    const int col0 = blockIdx.x * 128;
    const float* A_ = Amat + (size_t)g * NPG * NPG;
    const float* H_ = H + (size_t)g * NPG * DD;
    float* O_ = Out + (size_t)g * NPG * DD;
    const int tr = tid >> 4, tc = tid & 15;
    float acc[8][8] = {};
    const int ar = tid >> 1;
    const int ak = (tid & 1) * 8;
    const int bk = tid >> 4;
    const int bc = (tid & 15) * 8;
    for (int k0 = 0; k0 < 128; k0 += 16) {
        float4 av0 = *(const float4*)(A_ + (size_t)ar * 128 + k0 + ak);
        float4 av1 = *(const float4*)(A_ + (size_t)ar * 128 + k0 + ak + 4);
        float4 bv0 = *(const float4*)(H_ + (size_t)(k0 + bk) * 256 + col0 + bc);
        float4 bv1 = *(const float4*)(H_ + (size_t)(k0 + bk) * 256 + col0 + bc + 4);
        __syncthreads();
        As[ak + 0][ar] = av0.x; As[ak + 1][ar] = av0.y;
        As[ak + 2][ar] = av0.z; As[ak + 3][ar] = av0.w;
        As[ak + 4][ar] = av1.x; As[ak + 5][ar] = av1.y;
        As[ak + 6][ar] = av1.z; As[ak + 7][ar] = av1.w;
        *(float4*)&Bs[bk][bc] = bv0;
        *(float4*)&Bs[bk][bc + 4] = bv1;
        __syncthreads();
        mm_inner(As, Bs, tr, tc, acc);
    }
#pragma unroll
    for (int m = 0; m < 8; ++m) {
        float vals[8];
#pragma unroll
        for (int n = 0; n < 8; ++n) {
            int col = col0 + tc * 8 + n;
            float v = acc[m][n] + bias[col];
            if (do_relu) v = fmaxf(v, 0.0f);
            vals[n] = v;
        }
        float4 o0 = {vals[0], vals[1], vals[2], vals[3]};
        float4 o1 = {vals[4], vals[5], vals[6], vals[7]};
        float* p = O_ + (size_t)(tr * 8 + m) * 256 + col0 + tc * 8;
        *(float4*)p = o0;
        *(float4*)(p + 4) = o1;
    }
}

// ---------------- segment softmax over nodes within each graph --------------
// grid: (G), 256 threads; thread d handles feature column d.

__global__ __launch_bounds__(256) void k_segsm(float* __restrict__ T) {
    int g = blockIdx.x;
    int d = threadIdx.x;
    float* base = T + (size_t)g * NPG * DD + d;
    float m = -1e30f;
    for (int n = 0; n < NPG; ++n) m = fmaxf(m, base[n * DD]);
    float s = 0.0f;
    for (int n = 0; n < NPG; ++n) {
        float e = expf(base[n * DD] - m);
        base[n * DD] = e;
        s += e;
    }
    float inv = 1.0f / s;
    for (int n = 0; n < NPG; ++n) base[n * DD] *= inv;
}

// ---------------- fused bmm (a2^T @ x2) + Wl reduction ----------------------
// grid: (2, 2, G). P[d][e] = sum_n a2[g,n,d]*x2[g,n,e]; logits[g,c] += sum P*Wl

__global__ __launch_bounds__(256, 2) void k_bmm_red(const float* __restrict__ a2,
                                                    const float* __restrict__ x2,
                                                    const float* __restrict__ Wl,
                                                    float* __restrict__ logits) {
    __shared__ float As[16][128], Bs[16][128];
    __shared__ float red[256];
    const int tid = threadIdx.x;
    const int g = blockIdx.z;
    const int d0 = blockIdx.y * 128, e0 = blockIdx.x * 128;
    const float* a_ = a2 + (size_t)g * NPG * DD;
    const float* x_ = x2 + (size_t)g * NPG * DD;
    const int tr = tid >> 4, tc = tid & 15;
    float acc[8][8] = {};
    const int lk = tid >> 4;          // k index 0..15
    const int lc = (tid & 15) * 8;    // col offset
    for (int k0 = 0; k0 < 128; k0 += 16) {
        float4 av0 = *(const float4*)(a_ + (size_t)(k0 + lk) * 256 + d0 + lc);
        float4 av1 = *(const float4*)(a_ + (size_t)(k0 + lk) * 256 + d0 + lc + 4);
        float4 bv0 = *(const float4*)(x_ + (size_t)(k0 + lk) * 256 + e0 + lc);
        float4 bv1 = *(const float4*)(x_ + (size_t)(k0 + lk) * 256 + e0 + lc + 4);
        __syncthreads();
        *(float4*)&As[lk][lc] = av0;
        *(float4*)&As[lk][lc + 4] = av1;
        *(float4*)&Bs[lk][lc] = bv0;
        *(float4*)&Bs[lk][lc + 4] = bv1;
        __syncthreads();
        mm_inner(As, Bs, tr, tc, acc);
    }
    float p0 = 0.0f, p1 = 0.0f;
#pragma unroll
    for (int m = 0; m < 8; ++m)
#pragma unroll
        for (int n = 0; n < 8; ++n) {
            int d = d0 + tr * 8 + m;
            int e = e0 + tc * 8 + n;
            const float* w = Wl + ((size_t)d * 256 + e) * 2;
            p0 += acc[m][n] * w[0];
            p1 += acc[m][n] * w[1];
        }
    red[tid] = p0;
    __syncthreads();
    for (int s = 128; s > 0; s >>= 1) {
        if (tid < s) red[tid] += red[tid + s];
        __syncthreads();
    }
    if (tid == 0) atomicAdd(&logits[g * 2 + 0], red[0]);
    __syncthreads();
    red[tid] = p1;
    __syncthreads();
    for (int s = 128; s > 0; s >>= 1) {
        if (tid < s) red[tid] += red[tid + s];
        __syncthreads();
    }
    if (tid == 0) atomicAdd(&logits[g * 2 + 1], red[0]);
}

// ---------------- final 2-class softmax ----------------

__global__ void k_out(const float* __restrict__ logits, const float* __restrict__ bl,
                      float* __restrict__ out) {
    int g = blockIdx.x * blockDim.x + threadIdx.x;
    if (g < GG) {
        float l0 = logits[g * 2 + 0] + bl[0];
        float l1 = logits[g * 2 + 1] + bl[1];
        float m = fmaxf(l0, l1);
        float e0 = expf(l0 - m), e1 = expf(l1 - m);
        float inv = 1.0f / (e0 + e1);
        out[g * 2 + 0] = e0 * inv;
        out[g * 2 + 1] = e1 * inv;
    }
}

// ---------------- launcher ----------------

extern "C" void kernel_launch(void* const* d_in, const int* in_sizes, int n_in,
                              void* d_out, int out_size, void* d_ws, size_t ws_size,
                              hipStream_t stream) {
    const float* x   = (const float*)d_in[0];
    const int*   ei  = (const int*)d_in[1];
    const float* Wa1 = (const float*)d_in[3];
    const float* ba1 = (const float*)d_in[4];
    const float* Wa2 = (const float*)d_in[5];
    const float* ba2 = (const float*)d_in[6];
    const float* Wx1 = (const float*)d_in[7];
    const float* bx1 = (const float*)d_in[8];
    const float* Wx2 = (const float*)d_in[9];
    const float* bx2 = (const float*)d_in[10];
    const float* Wl  = (const float*)d_in[11];
    const float* bl  = (const float*)d_in[12];
    float* out = (float*)d_out;

    char* ws = (char*)d_ws;
    // layout: deg[N] | A[G*128*128] | b0[N*256] | b1[N*256] | b2[N*256] | logits[G*2]
    float* deg    = (float*)(ws);
    float* Amat   = (float*)(ws + 131072);
    float* b0     = (float*)(ws + 16908288);
    float* b1     = (float*)(ws + 50462720);
    float* b2     = (float*)(ws + 84017152);
    float* logits = (float*)(ws + 117571584);
    if (ws_size < 117573632) return;  // insufficient scratch; fail visibly

    const int* srcp = ei;
    const int* dstp = ei + EE;

    hipMemsetAsync(deg, 0, NN * 4, stream);
    hipMemsetAsync(Amat, 0, (size_t)GG * NPG * NPG * 4, stream);
    hipMemsetAsync(logits, 0, GG * 2 * 4, stream);

    k_deg<<<EE / 256, 256, 0, stream>>>(dstp, deg, EE);
    k_dinv<<<NN / 256, 256, 0, stream>>>(deg, NN);
    k_buildA<<<EE / 256, 256, 0, stream>>>(srcp, dstp, deg, Amat, EE);
    k_diagA<<<NN / 256, 256, 0, stream>>>(deg, Amat, NN);

    dim3 blk(256);
    // a-branch
    k_gemm_nodes<<<dim3(2, 256), blk, 0, stream>>>(x, Wa1, b0);
    k_prop<<<dim3(2, 1, GG), blk, 0, stream>>>(Amat, b0, ba1, b1, 1);
    k_gemm_nodes<<<dim3(2, 256), blk, 0, stream>>>(b1, Wa2, b0);
    k_prop<<<dim3(2, 1, GG), blk, 0, stream>>>(Amat, b0, ba2, b2, 0);
    k_segsm<<<GG, 256, 0, stream>>>(b2);
    // x-branch
    k_gemm_nodes<<<dim3(2, 256), blk, 0, stream>>>(x, Wx1, b0);
    k_prop<<<dim3(2, 1, GG), blk, 0, stream>>>(Amat, b0, bx1, b1, 1);
    k_gemm_nodes<<<dim3(2, 256), blk, 0, stream>>>(b1, Wx2, b0);
    k_prop<<<dim3(2, 1, GG), blk, 0, stream>>>(Amat, b0, bx2, b1, 1);
    // fused bmm + Wl reduce
    k_bmm_red<<<dim3(2, 2, GG), blk, 0, stream>>>(b2, b1, Wl, logits);
    k_out<<<1, 256, 0, stream>>>(logits, bl, out);
}

// Round 3
// 137.276 us; speedup vs baseline: 3.6499x; 3.6499x over previous
//
#include <hip/hip_runtime.h>
#include <hip/hip_bf16.h>

#define NN 32768
#define GG 256
#define NPG 128
#define EE 262144
#define DD 256

using s16x8 = __attribute__((ext_vector_type(8))) short;
using f16x8 = __attribute__((ext_vector_type(8))) _Float16;
using f32x4 = __attribute__((ext_vector_type(4))) float;

__device__ __forceinline__ short f2h(float f) {
    _Float16 h = (_Float16)f;          // v_cvt_f16_f32, RTN
    return __builtin_bit_cast(short, h);
}
__device__ __forceinline__ f16x8 ash(s16x8 v) { return __builtin_bit_cast(f16x8, v); }

// ---------------- graph preprocessing ----------------

__global__ void k_deg(const int* __restrict__ dst, float* __restrict__ deg, int e_count) {
    int e = blockIdx.x * 256 + threadIdx.x;
    if (e < e_count) atomicAdd(&deg[dst[e]], 1.0f);
}

__global__ void k_dinv(float* __restrict__ deg, int n) {
    int i = blockIdx.x * 256 + threadIdx.x;
    if (i < n) deg[i] = rsqrtf(deg[i] + 1.0f);
}

__global__ void k_buildA(const int* __restrict__ src, const int* __restrict__ dst,
                         const float* __restrict__ dinv, float* __restrict__ A, int e_count) {
    int e = blockIdx.x * 256 + threadIdx.x;
    if (e >= e_count) return;
    int s = src[e], d = dst[e];
    int g = d >> 7;
    int i = d & 127, j = s & 127;
    atomicAdd(&A[(((size_t)g * NPG) + i) * NPG + j], dinv[s] * dinv[d]);
}

__global__ void k_diagA(const float* __restrict__ dinv, float* __restrict__ A, int n) {
    int v = blockIdx.x * 256 + threadIdx.x;
    if (v < n) {
        int g = v >> 7, l = v & 127;
        A[(((size_t)g * NPG) + l) * NPG + l] += dinv[v] * dinv[v];
    }
}

// ---------------- pack kernels (fp32 -> fp16 MFMA fragment layouts) ----------
// A-frag chunk layout for an MxK operand (M=128): chunk ci = (kb*8 + rb)*64 + lane,
// lane = (r%16) | (((k%32)/8)<<4), elem j = k%8. Chunk holds row r, k0..k0+7 contiguous.

__global__ void k_packX(const float* __restrict__ X, short* __restrict__ Xp) {
    int t = blockIdx.x * 256 + threadIdx.x;   // 1048576 threads
    int row = t >> 5;
    int kc = t & 31;
    int g = row >> 7, r = row & 127;
    int kb = kc >> 2, q = kc & 3;
    int lane = (r & 15) | (q << 4);
    int rb = r >> 4;
    int ci = (kb * 8 + rb) * 64 + lane;
    const float* s = X + (size_t)row * 256 + kc * 8;
    f32x4 v0 = *(const f32x4*)s, v1 = *(const f32x4*)(s + 4);
    s16x8 o;
    o[0]=f2h(v0[0]); o[1]=f2h(v0[1]); o[2]=f2h(v0[2]); o[3]=f2h(v0[3]);
    o[4]=f2h(v1[0]); o[5]=f2h(v1[1]); o[6]=f2h(v1[2]); o[7]=f2h(v1[3]);
    *(s16x8*)(Xp + ((size_t)g * 4096 + ci) * 8) = o;
}

__global__ void k_packA(const float* __restrict__ A, short* __restrict__ Ap) {
    int t = blockIdx.x * 256 + threadIdx.x;   // 524288 threads
    int rowG = t >> 4;
    int kc = t & 15;
    int g = rowG >> 7, r = rowG & 127;
    int kb = kc >> 2, q = kc & 3;
    int lane = (r & 15) | (q << 4);
    int rb = r >> 4;
    int ci = (kb * 8 + rb) * 64 + lane;
    const float* s = A + (size_t)rowG * 128 + kc * 8;
    f32x4 v0 = *(const f32x4*)s, v1 = *(const f32x4*)(s + 4);
    s16x8 o;
    o[0]=f2h(v0[0]); o[1]=f2h(v0[1]); o[2]=f2h(v0[2]); o[3]=f2h(v0[3]);
    o[4]=f2h(v1[0]); o[5]=f2h(v1[1]); o[6]=f2h(v1[2]); o[7]=f2h(v1[3]);
    *(s16x8*)(Ap + ((size_t)g * 2048 + ci) * 8) = o;
}

// W [256][256] fp32 x4 -> B-frag: ci = (kb*16 + cn)*64 + lane,
// lane = (c%16) | (((k%32)/8)<<4), elem j = k%8. Chunk = column c, k0..k0+7.
__global__ void k_packW(const float* __restrict__ W0, const float* __restrict__ W1,
                        const float* __restrict__ W2, const float* __restrict__ W3,
                        short* __restrict__ Wp) {
    int t = blockIdx.x * 256 + threadIdx.x;   // 32768 threads
    int mat = t >> 13, ci = t & 8191;
    const float* W = (mat == 0) ? W0 : (mat == 1) ? W1 : (mat == 2) ? W2 : W3;
    int lane = ci & 63, t2 = ci >> 6;
    int cn = t2 & 15, kb = t2 >> 4;
    int c = cn * 16 + (lane & 15);
    int k0 = kb * 32 + (lane >> 4) * 8;
    s16x8 o;
#pragma unroll
    for (int j = 0; j < 8; ++j) o[j] = f2h(W[(size_t)(k0 + j) * 256 + c]);
    *(s16x8*)(Wp + ((size_t)mat * 8192 + ci) * 8) = o;
}

// Wl [65536][2] fp32 -> per-(tile,lane) 8 floats: [((db*16+eb)*64+l)*8 + r*2 + cls]
__global__ void k_packWl(const float* __restrict__ Wl, float* __restrict__ Wlp) {
    int t = blockIdx.x * 256 + threadIdx.x;   // 16384 threads
    int lane = t & 63, tile = t >> 6;
    int db = tile >> 4, eb = tile & 15;
    int q = lane >> 4, ce = lane & 15;
    float* dst = Wlp + (size_t)t * 8;
#pragma unroll
    for (int r = 0; r < 4; ++r)
#pragma unroll
        for (int cls = 0; cls < 2; ++cls)
            dst[r * 2 + cls] = Wl[(((size_t)(db * 16 + q * 4 + r) * 256) + eb * 16 + ce) * 2 + cls];
}

// ---------------- mega kernel ----------------
// One block (256 thr = 4 waves) per graph. Waves 2x2 over each 128x128 half.
// MODE 0: bias+relu -> act image (A-frag) in scRaw, copied to outG after both halves.
// MODE 1: raw conv out (bias cancels in softmax) -> fp32 LDS -> segment softmax -> outG (B-frag a2).
// MODE 2: bias+relu -> x2 image (B-frag) kept in scRaw for the bmm.

template<int MODE>
__device__ __forceinline__ void conv_stage(
    const short* __restrict__ actG, const short* __restrict__ Wp,
    const s16x8 (&agf)[4][4], const float* __restrict__ bias,
    short* __restrict__ outG, short* bhBuf, unsigned char* scRaw, int tid)
{
    const int lane = tid & 63, lq = lane >> 4, lm = lane & 15;
    const int w = tid >> 6, wr = w >> 1, wc = w & 1;
    short* scImg = (short*)scRaw;
    float* scf = (float*)scRaw;

    for (int cb = 0; cb < 2; ++cb) {
        __syncthreads();
        // ---- GEMM: H[:, cb*128 .. +128] = act @ W ----
        f32x4 acc[4][4];
#pragma unroll
        for (int m = 0; m < 4; ++m)
#pragma unroll
            for (int n = 0; n < 4; ++n) acc[m][n] = (f32x4){0.f, 0.f, 0.f, 0.f};
#pragma unroll
        for (int kb = 0; kb < 8; ++kb) {
            s16x8 af[4], bfr[4];
#pragma unroll
            for (int m = 0; m < 4; ++m)
                af[m] = *(const s16x8*)(actG + ((size_t)((kb * 8 + wr * 4 + m) * 64 + lane)) * 8);
#pragma unroll
            for (int n = 0; n < 4; ++n)
                bfr[n] = *(const s16x8*)(Wp + ((size_t)((kb * 16 + cb * 8 + wc * 4 + n) * 64 + lane)) * 8);
#pragma unroll
            for (int m = 0; m < 4; ++m)
#pragma unroll
                for (int n = 0; n < 4; ++n)
                    acc[m][n] = __builtin_amdgcn_mfma_f32_16x16x32_f16(ash(af[m]), ash(bfr[n]), acc[m][n], 0, 0, 0);
        }
        // scatter H (fp16) into BH B-frag layout
#pragma unroll
        for (int m = 0; m < 4; ++m)
#pragma unroll
            for (int n = 0; n < 4; ++n) {
                int c = wc * 64 + n * 16 + lm;
#pragma unroll
                for (int r = 0; r < 4; ++r) {
                    int nr = wr * 64 + m * 16 + lq * 4 + r;
                    int idx = ((c >> 4) * 4 + (nr >> 5)) * 64 + (lm | (((nr & 31) >> 3) << 4));
                    bhBuf[idx * 8 + (nr & 7)] = f2h(acc[m][n][r]);
                }
            }
        __syncthreads();
        // ---- PROP: O = A_g @ H ----
        f32x4 acc2[4][4];
#pragma unroll
        for (int m = 0; m < 4; ++m)
#pragma unroll
            for (int n = 0; n < 4; ++n) acc2[m][n] = (f32x4){0.f, 0.f, 0.f, 0.f};
#pragma unroll
        for (int kb = 0; kb < 4; ++kb) {
            s16x8 bfr[4];
#pragma unroll
            for (int n = 0; n < 4; ++n)
                bfr[n] = *(const s16x8*)(bhBuf + ((size_t)(((wc * 4 + n) * 4 + kb) * 64 + lane)) * 8);
#pragma unroll
            for (int m = 0; m < 4; ++m)
#pragma unroll
                for (int n = 0; n < 4; ++n)
                    acc2[m][n] = __builtin_amdgcn_mfma_f32_16x16x32_f16(ash(agf[m][kb]), ash(bfr[n]), acc2[m][n], 0, 0, 0);
        }
        float bn[4];
        if constexpr (MODE != 1) {
#pragma unroll
            for (int n = 0; n < 4; ++n) bn[n] = bias[cb * 128 + wc * 64 + n * 16 + lm];
        }
#pragma unroll
        for (int m = 0; m < 4; ++m)
#pragma unroll
            for (int n = 0; n < 4; ++n) {
                int cl = wc * 64 + n * 16 + lm;
                int cg = cb * 128 + cl;
#pragma unroll
                for (int r = 0; r < 4; ++r) {
                    int nr = wr * 64 + m * 16 + lq * 4 + r;
                    float v = acc2[m][n][r];
                    if constexpr (MODE == 0) {
                        v = fmaxf(v + bn[n], 0.f);
                        int idx = ((cg >> 5) * 8 + (nr >> 4)) * 64 + ((nr & 15) | (((cg & 31) >> 3) << 4));
                        scImg[idx * 8 + (cg & 7)] = f2h(v);
                    } else if constexpr (MODE == 1) {
                        scf[cl * 128 + (nr ^ ((cl & 7) << 2))] = v;   // fp32, XOR-swizzled
                    } else {
                        v = fmaxf(v + bn[n], 0.f);
                        int idx = ((cg >> 4) * 4 + (nr >> 5)) * 64 + ((cg & 15) | (((nr & 31) >> 3) << 4));
                        scImg[idx * 8 + (nr & 7)] = f2h(v);
                    }
                }
            }
        if constexpr (MODE == 1) {
            __syncthreads();
            const int c = tid >> 1, h = tid & 1, n0 = h * 64;
            const int sw = (c & 7) << 2;
            float vals[64];
#pragma unroll
            for (int i = 0; i < 16; ++i) {
                f32x4 v4 = *(const f32x4*)&scf[c * 128 + ((n0 + i * 4) ^ sw)];
                vals[i*4+0] = v4[0]; vals[i*4+1] = v4[1]; vals[i*4+2] = v4[2]; vals[i*4+3] = v4[3];
            }
            float pm = -1e30f;
#pragma unroll
            for (int j = 0; j < 64; ++j) pm = fmaxf(pm, vals[j]);
            float* red = (float*)bhBuf;
            red[tid] = pm;
            __syncthreads();
            float mfin = fmaxf(red[2 * c], red[2 * c + 1]);
            __syncthreads();
            float ps = 0.f;
#pragma unroll
            for (int j = 0; j < 64; ++j) { vals[j] = __expf(vals[j] - mfin); ps += vals[j]; }
            red[tid] = ps;
            __syncthreads();
            float sinv = 1.0f / (red[2 * c] + red[2 * c + 1]);
            int cg = cb * 128 + c;
#pragma unroll
            for (int i = 0; i < 8; ++i) {
                int nn = n0 + i * 8;
                s16x8 ob;
#pragma unroll
                for (int j = 0; j < 8; ++j) ob[j] = f2h(vals[i * 8 + j] * sinv);
                int idx = ((cg >> 4) * 4 + (nn >> 5)) * 64 + ((cg & 15) | (((nn & 31) >> 3) << 4));
                *(s16x8*)(outG + (size_t)idx * 8) = ob;
            }
        }
    }
    if constexpr (MODE == 0) {
        __syncthreads();
        for (int i = tid; i < 4096; i += 256)
            *(s16x8*)(outG + (size_t)i * 8) = *(const s16x8*)(scImg + (size_t)i * 8);
    }
}

__global__ __launch_bounds__(256, 1) void k_mega(
    const short* __restrict__ Xp, const short* __restrict__ Ap,
    const short* __restrict__ Wp, const float* __restrict__ Wlp,
    const float* __restrict__ ba1, const float* __restrict__ bx1,
    const float* __restrict__ bx2, const float* __restrict__ bl,
    short* __restrict__ gact, short* __restrict__ ga2,
    float* __restrict__ out)
{
    __shared__ __align__(16) short bhBuf[2048 * 8];        // 32 KB
    __shared__ __align__(16) unsigned char scRaw[65536];   // 64 KB
    const int tid = threadIdx.x;
    const int g = blockIdx.x;
    const int lane = tid & 63;
    const int w = tid >> 6, wr = w >> 1;

    const short* xg = Xp + (size_t)g * 4096 * 8;
    const short* apg = Ap + (size_t)g * 2048 * 8;
    short* actg = gact + (size_t)g * 4096 * 8;
    short* a2g = ga2 + (size_t)g * 4096 * 8;

    s16x8 agf[4][4];
#pragma unroll
    for (int m = 0; m < 4; ++m)
#pragma unroll
        for (int kb = 0; kb < 4; ++kb)
            agf[m][kb] = *(const s16x8*)(apg + ((size_t)((kb * 8 + wr * 4 + m) * 64 + lane)) * 8);

    conv_stage<0>(xg,   Wp + (size_t)0 * 8192 * 8, agf, ba1, actg, bhBuf, scRaw, tid);
    __syncthreads();
    conv_stage<1>(actg, Wp + (size_t)1 * 8192 * 8, agf, nullptr, a2g, bhBuf, scRaw, tid);
    __syncthreads();
    conv_stage<0>(xg,   Wp + (size_t)2 * 8192 * 8, agf, bx1, actg, bhBuf, scRaw, tid);
    __syncthreads();
    conv_stage<2>(actg, Wp + (size_t)3 * 8192 * 8, agf, bx2, nullptr, bhBuf, scRaw, tid);
    __syncthreads();

    // ---- bmm P = a2^T @ x2 fused with Wl reduction ----
    const short* x2img = (const short*)scRaw;
    s16x8 pa[4][4];
#pragma unroll
    for (int dt = 0; dt < 4; ++dt)
#pragma unroll
        for (int kb = 0; kb < 4; ++kb)
            pa[dt][kb] = *(const s16x8*)(a2g + ((size_t)(((w * 4 + dt) * 4 + kb) * 64 + lane)) * 8);
    float p0 = 0.f, p1 = 0.f;
    for (int et = 0; et < 16; ++et) {
        s16x8 xb[4];
#pragma unroll
        for (int kb = 0; kb < 4; ++kb)
            xb[kb] = *(const s16x8*)(x2img + ((size_t)((et * 4 + kb) * 64 + lane)) * 8);
#pragma unroll
        for (int dt = 0; dt < 4; ++dt) {
            f32x4 acc = (f32x4){0.f, 0.f, 0.f, 0.f};
#pragma unroll
            for (int kb = 0; kb < 4; ++kb)
                acc = __builtin_amdgcn_mfma_f32_16x16x32_f16(ash(pa[dt][kb]), ash(xb[kb]), acc, 0, 0, 0);
            const float* wl = Wlp + (((size_t)(w * 4 + dt) * 16 + et) * 64 + lane) * 8;
            f32x4 w0 = *(const f32x4*)wl;
            f32x4 w1 = *(const f32x4*)(wl + 4);
            p0 += acc[0] * w0[0] + acc[1] * w0[2] + acc[2] * w1[0] + acc[3] * w1[2];
            p1 += acc[0] * w0[1] + acc[1] * w0[3] + acc[2] * w1[1] + acc[3] * w1[3];
        }
    }
    float* red = (float*)bhBuf;
    red[tid] = p0; red[256 + tid] = p1;
    __syncthreads();
    for (int s = 128; s > 0; s >>= 1) {
        if (tid < s) { red[tid] += red[tid + s]; red[256 + tid] += red[256 + tid + s]; }
        __syncthreads();
    }
    if (tid == 0) {
        float l0 = red[0] + bl[0], l1 = red[256] + bl[1];
        float mm = fmaxf(l0, l1);
        float e0 = __expf(l0 - mm), e1 = __expf(l1 - mm);
        float inv = 1.0f / (e0 + e1);
        out[g * 2 + 0] = e0 * inv;
        out[g * 2 + 1] = e1 * inv;
    }
}

// ---------------- launcher ----------------

extern "C" void kernel_launch(void* const* d_in, const int* in_sizes, int n_in,
                              void* d_out, int out_size, void* d_ws, size_t ws_size,
                              hipStream_t stream) {
    const float* x   = (const float*)d_in[0];
    const int*   ei  = (const int*)d_in[1];
    const float* Wa1 = (const float*)d_in[3];
    const float* ba1 = (const float*)d_in[4];
    const float* Wa2 = (const float*)d_in[5];
    const float* Wx1 = (const float*)d_in[7];
    const float* bx1 = (const float*)d_in[8];
    const float* Wx2 = (const float*)d_in[9];
    const float* bx2 = (const float*)d_in[10];
    const float* Wl  = (const float*)d_in[11];
    const float* bl  = (const float*)d_in[12];
    float* out = (float*)d_out;

    char* ws = (char*)d_ws;
    float* deg  = (float*)(ws + 0);          // 128 KB
    float* Afp  = (float*)(ws + 131072);     // 16 MB
    short* Xp   = (short*)(ws + 16908288);   // 16 MB
    short* Wpk  = (short*)(ws + 33685504);   // 512 KB
    float* Wlp  = (float*)(ws + 34209792);   // 512 KB
    short* gact = (short*)(ws + 34734080);   // 16 MB
    short* ga2  = (short*)(ws + 51511296);   // 16 MB
    short* Ap   = (short*)(ws + 68288512);   // 8 MB
    if (ws_size < 76677120) return;

    const int* srcp = ei;
    const int* dstp = ei + EE;

    hipMemsetAsync(deg, 0, NN * 4, stream);
    hipMemsetAsync(Afp, 0, (size_t)GG * NPG * NPG * 4, stream);

    k_deg<<<EE / 256, 256, 0, stream>>>(dstp, deg, EE);
    k_dinv<<<NN / 256, 256, 0, stream>>>(deg, NN);
    k_buildA<<<EE / 256, 256, 0, stream>>>(srcp, dstp, deg, Afp, EE);
    k_diagA<<<NN / 256, 256, 0, stream>>>(deg, Afp, NN);

    k_packA<<<2048, 256, 0, stream>>>(Afp, Ap);
    k_packX<<<4096, 256, 0, stream>>>(x, Xp);
    k_packW<<<128, 256, 0, stream>>>(Wa1, Wa2, Wx1, Wx2, Wpk);
    k_packWl<<<64, 256, 0, stream>>>(Wl, Wlp);

    k_mega<<<GG, 256, 0, stream>>>(Xp, Ap, Wpk, Wlp, ba1, bx1, bx2, bl, gact, ga2, out);
}